// Round 5
// baseline (223.719 us; speedup 1.0000x reference)
//
#include <hip/hip_runtime.h>
#include <stdint.h>

#define A 15
#define H_ 34
#define W_ 34
#define HW (H_*W_)
#define N (A*HW)            // 17340
#define MAX_CAND 3000
#define TOP_N 300
#define NWORDS 47           // ceil(3000/64)
#define CHUNK_W 3008        // 64 rows * 47 words per chunk
#define HSIZE 65536         // 16-bit histogram
#define TILE 4096           // rank LDS tile
#define ITILE 16            // iou rows per block

__constant__ float c_aw[A] = {9.232984f, 16.0f, 27.712813f, 18.465969f, 32.0f, 55.425626f,
                              36.931937f, 64.0f, 110.851252f, 73.863875f, 128.0f, 221.702503f,
                              147.72775f, 256.0f, 443.405007f};
__constant__ float c_ah[A] = {27.72668f, 16.0f, 9.237604f, 55.453359f, 32.0f, 18.475209f,
                              110.906719f, 64.0f, 36.950417f, 221.813438f, 128.0f, 73.900834f,
                              443.626876f, 256.0f, 147.801669f};

// ---------------------------------------------------------------------------
// K1: decode boxes/scores/keys; histogram top-16 key bits; zero kpm.
// Exact reference op order; __f*_rn blocks FMA contraction.
// ---------------------------------------------------------------------------
__global__ __launch_bounds__(256) void k_boxes(
    const float* __restrict__ cls, const float* __restrict__ pred,
    const int* __restrict__ iminfo,
    float4* __restrict__ boxes, float2* __restrict__ scores,
    unsigned long long* __restrict__ keys,
    unsigned int* __restrict__ hist, unsigned long long* __restrict__ kpm)
{
    int m = blockIdx.x * 256 + threadIdx.x;
    if (m >= N) return;
    if (m < NWORDS) kpm[m] = 0ull;

    int a  = m % A;
    int hw = m / A;
    int w  = hw % W_;
    int h  = hw / W_;

    float ow = (float)iminfo[1];
    float oh = (float)iminfo[0];

    float aw = c_aw[a], ah = c_ah[a];
    float xm = __fmul_rn(-0.5f, __fsub_rn(aw, 1.0f));
    float ym = __fmul_rn(-0.5f, __fsub_rn(ah, 1.0f));
    float sxw = (float)(w * 8);
    float syh = (float)(h * 8);
    float x1 = __fadd_rn(sxw, xm);
    float y1 = __fadd_rn(syh, ym);
    float x2 = __fadd_rn(sxw, -xm);
    float y2 = __fadd_rn(syh, -ym);

    float widths  = __fadd_rn(__fsub_rn(x2, x1), 1.0f);
    float heights = __fadd_rn(__fsub_rn(y2, y1), 1.0f);
    float ctr_x = __fadd_rn(x1, __fmul_rn(0.5f, __fsub_rn(widths, 1.0f)));
    float ctr_y = __fadd_rn(y1, __fmul_rn(0.5f, __fsub_rn(heights, 1.0f)));

    const float std0 = 0.12677f,   std1 = 0.095741f, std2 = 0.3173f,    std3 = 0.281042f;
    const float mu0  = 0.000437f,  mu1  = 0.002586f, mu2  = -0.123953f, mu3  = -0.081469f;
    int pb = a * 4 * HW + hw;
    float d0 = __fadd_rn(__fmul_rn(pred[pb + 0 * HW], std0), mu0);
    float d1 = __fadd_rn(__fmul_rn(pred[pb + 1 * HW], std1), mu1);
    float d2 = __fadd_rn(__fmul_rn(pred[pb + 2 * HW], std2), mu2);
    float d3 = __fadd_rn(__fmul_rn(pred[pb + 3 * HW], std3), mu3);

    float pcx = __fadd_rn(__fmul_rn(d0, widths),  ctr_x);
    float pcy = __fadd_rn(__fmul_rn(d1, heights), ctr_y);
    float pw  = __fmul_rn(expf(d2), widths);
    float ph  = __fmul_rn(expf(d3), heights);

    float hpw = __fmul_rn(0.5f, __fsub_rn(pw, 1.0f));
    float hph = __fmul_rn(0.5f, __fsub_rn(ph, 1.0f));
    float bx1 = __fsub_rn(pcx, hpw);
    float by1 = __fsub_rn(pcy, hph);
    float bx2 = __fadd_rn(pcx, hpw);
    float by2 = __fadd_rn(pcy, hph);

    float ow1 = __fsub_rn(ow, 1.0f), oh1 = __fsub_rn(oh, 1.0f);
    bx1 = fminf(fmaxf(bx1, 0.0f), ow1);
    by1 = fminf(fmaxf(by1, 0.0f), oh1);
    bx2 = fminf(fmaxf(bx2, 0.0f), ow1);
    by2 = fminf(fmaxf(by2, 0.0f), oh1);

    float s0 = cls[a * HW + hw];
    float s1 = cls[(A + a) * HW + hw];

    float wsv = __fadd_rn(__fsub_rn(bx2, bx1), 1.0f);
    float hsv = __fadd_rn(__fsub_rn(by2, by1), 1.0f);
    bool keep = (s1 > 0.2f) && ((wsv >= 6.16056f) || (hsv >= 6.16056f));
    float masked = keep ? s1 : -1e30f;

    boxes[m]  = make_float4(bx1, by1, bx2, by2);
    scores[m] = make_float2(s0, s1);

    unsigned int fb = __float_as_uint(masked);
    fb = (fb & 0x80000000u) ? ~fb : (fb | 0x80000000u);
    unsigned long long key = ((unsigned long long)fb << 32) | (unsigned int)(~(unsigned int)m);
    keys[m] = key;
    atomicAdd(&hist[(unsigned int)(key >> 48)], 1u);
}

// ---------------------------------------------------------------------------
// K2: single block. Suffix-scan 65536-bucket histogram -> bucket B of the
// 3000th-largest key; compact subset {hi >= B} (size S >= 3000 always).
// ---------------------------------------------------------------------------
__global__ __launch_bounds__(1024) void k_thresh(
    const unsigned long long* __restrict__ keys,
    const unsigned int* __restrict__ hist,
    unsigned long long* __restrict__ skeys, int* __restrict__ sidx,
    int* __restrict__ control)
{
    __shared__ int tsum[1024];
    __shared__ int sB;
    __shared__ int cnt;
    int t = threadIdx.x;
    int base = t * 64;

    // per-thread chunk sum (64 buckets, int4 loads)
    int local = 0;
    {
        const int4* h4 = (const int4*)hist;
        #pragma unroll
        for (int q = 0; q < 16; ++q) {
            int4 v = h4[t * 16 + q];
            local += v.x + v.y + v.z + v.w;
        }
    }
    tsum[t] = local;
    __syncthreads();

    // Hillis-Steele inclusive SUFFIX scan over 1024 thread sums
    for (int d = 1; d < 1024; d <<= 1) {
        int v = (t + d < 1024) ? tsum[t + d] : 0;
        __syncthreads();
        tsum[t] += v;
        __syncthreads();
    }

    int suf_self = tsum[t];
    int suf_next = (t < 1023) ? tsum[t + 1] : 0;
    if (t == 0) cnt = 0;

    // exactly one thread has the crossing: suf_self >= 3000 > suf_next
    if (suf_self >= MAX_CAND && suf_next < MAX_CAND) {
        const int4* h4 = (const int4*)hist;
        int4 hv[16];
        #pragma unroll
        for (int q = 0; q < 16; ++q) hv[q] = h4[t * 16 + q];
        int acc = suf_next;
        int B = base;
        bool found = false;
        #pragma unroll
        for (int q = 15; q >= 0; --q) {
            if (!found) { acc += hv[q].w; if (acc >= MAX_CAND) { B = base + q*4 + 3; found = true; } }
            if (!found) { acc += hv[q].z; if (acc >= MAX_CAND) { B = base + q*4 + 2; found = true; } }
            if (!found) { acc += hv[q].y; if (acc >= MAX_CAND) { B = base + q*4 + 1; found = true; } }
            if (!found) { acc += hv[q].x; if (acc >= MAX_CAND) { B = base + q*4 + 0; found = true; } }
        }
        sB = B;
    }
    __syncthreads();

    int B = sB;
    for (int i0 = 0; i0 < N; i0 += 1024) {
        int i = i0 + t;
        if (i < N) {
            unsigned long long k = keys[i];
            if ((int)(k >> 48) >= B) {
                int slot = atomicAdd(&cnt, 1);
                skeys[slot] = k;
                sidx[slot]  = i;
            }
        }
    }
    __syncthreads();
    if (t == 0) control[0] = cnt;
}

// ---------------------------------------------------------------------------
// K3: exact rank within subset (== global rank for top-3000 members) from a
// single LDS tile; scatter winners straight into candidate slots + kpm bit.
// ---------------------------------------------------------------------------
__global__ __launch_bounds__(256) void k_rank2(
    const int* __restrict__ control,
    const unsigned long long* __restrict__ skeys, const int* __restrict__ sidx,
    const float4* __restrict__ boxes, const float2* __restrict__ scores,
    float4* __restrict__ cboxes, float2* __restrict__ cscores,
    unsigned long long* __restrict__ kpm)
{
    __shared__ unsigned long long tile[TILE];
    int S = control[0];
    if (blockIdx.x * 256 >= S) return;   // uniform per block
    int t = threadIdx.x;
    int i = blockIdx.x * 256 + t;
    unsigned long long mykey = (i < S) ? skeys[i] : 0ull;

    int cnt = 0;
    for (int bse = 0; bse < S; bse += TILE) {
        int n = min(TILE, S - bse);
        __syncthreads();
        for (int k = t; k < n; k += 256) tile[k] = skeys[bse + k];
        __syncthreads();
        int k = 0;
        for (; k + 8 <= n; k += 8) {
            #pragma unroll
            for (int u = 0; u < 8; ++u) cnt += (tile[k + u] > mykey) ? 1 : 0;
        }
        for (; k < n; ++k) cnt += (tile[k] > mykey) ? 1 : 0;
    }

    if (i < S && cnt < MAX_CAND) {
        int orig = sidx[i];
        cboxes[cnt]  = boxes[orig];
        cscores[cnt] = scores[orig];
        unsigned int fb = (unsigned int)(mykey >> 32);
        float masked = (fb & 0x80000000u) ? __uint_as_float(fb & 0x7fffffffu)
                                          : __uint_as_float(~fb);
        if (masked > (-1e30f * 0.5f))
            atomicOr(&kpm[cnt >> 6], 1ull << (cnt & 63));
    }
}

// ---------------------------------------------------------------------------
// K4: suppression bitmask; 16 i-rows/block, all 3000 boxes staged in LDS.
// bit j of row i set iff iou(i,j)>0.7 && j>i.
// ---------------------------------------------------------------------------
__global__ __launch_bounds__(256) void k_iou(
    const float4* __restrict__ cboxes, unsigned long long* __restrict__ sup)
{
    __shared__ float4 bx[MAX_CAND];   // 48 KB
    int t = threadIdx.x;
    for (int k = t; k < MAX_CAND; k += 256) bx[k] = cboxes[k];
    __syncthreads();

    int lane = t & 63;
    int wave = t >> 6;
    int i0 = blockIdx.x * ITILE + wave * (ITILE / 4);

    for (int ii = 0; ii < ITILE / 4; ++ii) {
        int i = i0 + ii;
        if (i >= MAX_CAND) continue;
        float4 bi = bx[i];
        float area_i = __fmul_rn(__fsub_rn(bi.z, bi.x), __fsub_rn(bi.w, bi.y));
        for (int w = 0; w < NWORDS; ++w) {
            int j = w * 64 + lane;
            bool p = false;
            if (w * 64 + 63 > i && j < MAX_CAND && j > i) {
                float4 bj = bx[j];
                float iw = fmaxf(__fsub_rn(fminf(bi.z, bj.z), fmaxf(bi.x, bj.x)), 0.0f);
                float ih = fmaxf(__fsub_rn(fminf(bi.w, bj.w), fmaxf(bi.y, bj.y)), 0.0f);
                float inter  = __fmul_rn(iw, ih);
                float area_j = __fmul_rn(__fsub_rn(bj.z, bj.x), __fsub_rn(bj.w, bj.y));
                float denom  = fmaxf(__fsub_rn(__fadd_rn(area_i, area_j), inter), 1e-12f);
                p = (inter / denom) > 0.7f;
            }
            unsigned long long msk = __ballot(p);
            if (lane == 0) sup[(size_t)i * NWORDS + w] = msk;
        }
    }
}

// ---------------------------------------------------------------------------
// K5: chunked greedy NMS with early exit once kept>=300, nonzero-row skip,
// fixed-trip predicated fold, parallel output.
// ---------------------------------------------------------------------------
__global__ __launch_bounds__(1024) void k_nms_out(
    const unsigned long long* __restrict__ sup,
    const unsigned long long* __restrict__ kpm,
    const float4* __restrict__ cboxes, const float2* __restrict__ cscores,
    float* __restrict__ out)
{
    __shared__ unsigned long long buf[2][CHUNK_W];
    __shared__ unsigned long long kp[NWORDS + 1];
    __shared__ int sel[TOP_N];
    __shared__ int s_stop;

    int tid  = threadIdx.x;
    int lane = tid & 63;
    int wave = tid >> 6;

    for (int t = tid; t < TOP_N * 7; t += 1024) out[t] = 0.0f;
    for (int t = tid; t < TOP_N; t += 1024) sel[t] = -1;

    if (tid < NWORDS) kp[tid] = kpm[tid];

    {
        unsigned long long v0 = sup[tid];
        unsigned long long v1 = sup[tid + 1024];
        unsigned long long v2 = (tid + 2048 < CHUNK_W) ? sup[tid + 2048] : 0ull;
        buf[0][tid] = v0;
        buf[0][tid + 1024] = v1;
        if (tid + 2048 < CHUNK_W) buf[0][tid + 2048] = v2;
    }
    __syncthreads();

    int kept_total = 0;
    for (int w = 0; w < NWORDS; ++w) {
        int cur = w & 1;
        bool havnext = (w + 1 < NWORDS);

        unsigned long long v0 = 0, v1 = 0, v2 = 0;
        if (havnext) {
            const unsigned long long* src = sup + (size_t)(w + 1) * CHUNK_W;
            v0 = src[tid];
            v1 = src[tid + 1024];
            v2 = (tid + 2048 < CHUNK_W) ? src[tid + 2048] : 0ull;
        }

        if (wave == 0) {
            unsigned long long intra = buf[cur][lane * NWORDS + w];
            unsigned long long nz = __ballot(intra != 0ull);
            unsigned long long kw = kp[w];
            unsigned long long rem = kw & nz;
            while (rem) {
                int b = __ffsll((long long)rem) - 1;
                rem &= rem - 1;
                if ((kw >> b) & 1ull) {
                    unsigned long long row = __shfl(intra, b, 64);
                    kw  &= ~row;
                    rem &= ~row;
                }
            }
            if (lane == 0) kp[w] = kw;
            kept_total += __popcll(kw);
            bool stop = (kept_total >= TOP_N) || !havnext;
            if (lane == 0) s_stop = stop ? 1 : 0;

            if (!stop && lane < NWORDS && lane > w) {
                unsigned long long comb = 0;
                #pragma unroll 8
                for (int b = 0; b < 64; ++b) {
                    unsigned long long r = buf[cur][b * NWORDS + lane];
                    if ((kw >> b) & 1ull) comb |= r;
                }
                kp[lane] &= ~comb;
            }
        }

        if (havnext) {
            int nxt = cur ^ 1;
            buf[nxt][tid] = v0;
            buf[nxt][tid + 1024] = v1;
            if (tid + 2048 < CHUNK_W) buf[nxt][tid + 2048] = v2;
        }
        __syncthreads();
        if (s_stop) break;
    }

    if (wave == 0) {
        unsigned long long kw = (lane < NWORDS) ? kp[lane] : 0ull;
        int cnt = __popcll(kw);
        int pre = cnt;
        for (int d = 1; d < 64; d <<= 1) {
            int o = __shfl_up(pre, d, 64);
            if (lane >= d) pre += o;
        }
        int prefix = pre - cnt;
        while (kw && prefix < TOP_N) {
            int b = __ffsll((long long)kw) - 1;
            kw &= kw - 1;
            sel[prefix] = lane * 64 + b;
            prefix++;
        }
    }
    __syncthreads();

    if (tid < TOP_N) {
        int j = sel[tid];
        if (j >= 0) {
            float4 bx = cboxes[j];
            float2 sc = cscores[j];
            out[tid * 5 + 0] = 0.0f;
            out[tid * 5 + 1] = bx.x;
            out[tid * 5 + 2] = bx.y;
            out[tid * 5 + 3] = bx.z;
            out[tid * 5 + 4] = bx.w;
            out[TOP_N * 5 + tid * 2 + 0] = sc.x;
            out[TOP_N * 5 + tid * 2 + 1] = sc.y;
        }
    }
}

// ---------------------------------------------------------------------------
extern "C" void kernel_launch(void* const* d_in, const int* in_sizes, int n_in,
                              void* d_out, int out_size, void* d_ws, size_t ws_size,
                              hipStream_t stream) {
    const float* cls    = (const float*)d_in[0];
    const float* pred   = (const float*)d_in[1];
    const int*   iminfo = (const int*)d_in[2];
    float* out = (float*)d_out;

    char* p = (char*)d_ws;
    auto alloc = [&](size_t bytes) -> char* {
        char* q = p;
        p += (bytes + 255) & ~(size_t)255;
        return q;
    };
    float4* boxes  = (float4*)alloc((size_t)N * sizeof(float4));
    float2* scores = (float2*)alloc((size_t)N * sizeof(float2));
    unsigned long long* keys  = (unsigned long long*)alloc((size_t)N * 8);
    unsigned long long* skeys = (unsigned long long*)alloc((size_t)N * 8);
    int* sidx     = (int*)alloc((size_t)N * 4);
    unsigned int* hist = (unsigned int*)alloc((size_t)HSIZE * 4);
    int* control  = (int*)alloc(256);
    float4* cboxes  = (float4*)alloc((size_t)MAX_CAND * sizeof(float4));
    float2* cscores = (float2*)alloc((size_t)MAX_CAND * sizeof(float2));
    unsigned long long* kpm = (unsigned long long*)alloc((size_t)NWORDS * 8);
    unsigned long long* sup = (unsigned long long*)alloc((size_t)MAX_CAND * NWORDS * 8);

    hipMemsetAsync(hist, 0, (size_t)HSIZE * 4, stream);

    int nb = (N + 255) / 256;  // 68
    k_boxes <<<nb, 256, 0, stream>>>(cls, pred, iminfo, boxes, scores, keys, hist, kpm);
    k_thresh<<<1, 1024, 0, stream>>>(keys, hist, skeys, sidx, control);
    k_rank2 <<<nb, 256, 0, stream>>>(control, skeys, sidx, boxes, scores, cboxes, cscores, kpm);
    k_iou   <<<(MAX_CAND + ITILE - 1) / ITILE, 256, 0, stream>>>(cboxes, sup);
    k_nms_out<<<1, 1024, 0, stream>>>(sup, kpm, cboxes, cscores, out);
}